// Round 1
// baseline (1714.732 us; speedup 1.0000x reference)
//
#include <hip/hip_runtime.h>
#include <math.h>

#define Bn  16
#define Nn  127
#define NP  256
#define NSQ (NP*NP)       // 65536
#define RSZ (Nn*Nn)       // 16129

// ---------------- static device workspace ----------------
__device__ float2 g_CA[Bn*4*NSQ];   // 33.5 MB
__device__ float2 g_CB[Bn*4*NSQ];   // 33.5 MB
__device__ float  g_x[Bn*RSZ];
__device__ float  g_r[Bn*RSZ];
__device__ float2 g_W1 [Bn*4*9];    // [b][co][ci=0][3][3]
__device__ float2 g_W1T[Bn*4*9];    // [b][co=0][ci][3][3]
__device__ float2 g_W2 [Bn*16*9];   // [b][co][ci][3][3]
__device__ float2 g_W2T[Bn*16*9];
__device__ float2 g_W3 [Bn*4*9];    // [b][co=0][ci][3][3]
__device__ float2 g_W3T[Bn*4*9];    // [b][co][ci=0][3][3]
__device__ int    g_K;

// ---------------- init: K, zero x, canonical weights ----------------
__global__ void init_kernel(const float* __restrict__ w1r, const float* __restrict__ w1i,
                            const float* __restrict__ w2r, const float* __restrict__ w2i,
                            const float* __restrict__ w3r, const float* __restrict__ w3i,
                            const int* __restrict__ epoch)
{
    int tid = threadIdx.x;
    if (tid == 0) {
        int e = epoch[0];
        int K = (e - 1) / 40 + 1;
        if (K > 10) K = 10;
        if (K < 1)  K = 1;
        g_K = K;
    }
    for (int i = tid; i < Bn*RSZ; i += 256) g_x[i] = 0.f;

    // w1: [16,4,1,3,3]; w3: [16,1,4,3,3] -> both flat [16][4][9]
    for (int o = tid; o < Bn*36; o += 256) {
        int k = o % 9;
        int a = k / 3, bb = k % 3;
        int c = (o / 9) % 4;
        int b = o / 36;
        int src = b*36 + c*9 + bb*3 + a;   // channel-swapped + spatial transpose
        g_W1 [o] = make_float2(w1r[o],  w1i[o]);
        g_W1T[o] = make_float2(w1r[src], -w1i[src]);  // conj(w1[b][c][0][bb][a])
        g_W3 [o] = make_float2(w3r[o],  w3i[o]);
        g_W3T[o] = make_float2(w3r[src], -w3i[src]);  // conj(w3[b][0][c][bb][a])
    }
    // w2: [16,4,4,3,3]
    for (int o = tid; o < Bn*144; o += 256) {
        int k = o % 9;
        int a = k / 3, bb = k % 3;
        int ci = (o / 9) % 4;
        int co = (o / 36) % 4;
        int b  = o / 144;
        int src = b*144 + ci*36 + co*9 + bb*3 + a;    // w2[b][ci][co][bb][a]
        g_W2 [o] = make_float2(w2r[o],  w2i[o]);
        g_W2T[o] = make_float2(w2r[src], -w2i[src]);
    }
}

// ---------------- Jacobi: 20 steps + final residual, one sample per block ----------------
__global__ __launch_bounds__(1024) void jacobi_kernel(const float* __restrict__ f,
                                                      const float* __restrict__ kA, int it)
{
    if (it >= g_K) return;
    __shared__ float xs[Nn*128];
    int b = blockIdx.x, tid = threadIdx.x;
    float ka[9];
#pragma unroll
    for (int k = 0; k < 9; k++) ka[k] = kA[b*9 + k];
    float tau = 0.5f / ka[4];

    float fv[16], xv[16];
    int   ii[16], jj[16];
#pragma unroll
    for (int k = 0; k < 16; k++) {
        int e = tid + k*1024;
        if (e < RSZ) {
            fv[k] = f[b*RSZ + e];
            xv[k] = g_x[b*RSZ + e];
            ii[k] = e / Nn; jj[k] = e - ii[k]*Nn;
        } else { fv[k] = 0.f; xv[k] = 0.f; ii[k] = 0; jj[k] = 0; }
    }

    for (int itj = 0; itj <= 20; itj++) {
        __syncthreads();
#pragma unroll
        for (int k = 0; k < 16; k++) {
            int e = tid + k*1024;
            if (e < RSZ) xs[ii[k]*128 + jj[k]] = xv[k];
        }
        __syncthreads();
#pragma unroll
        for (int k = 0; k < 16; k++) {
            int e = tid + k*1024;
            if (e >= RSZ) continue;
            float conv = 0.f;
            int i0 = ii[k], j0 = jj[k];
#pragma unroll
            for (int a = 0; a < 3; a++) {
                int si = i0 + a - 1;
                if (si < 0 || si >= Nn) continue;
#pragma unroll
                for (int b2 = 0; b2 < 3; b2++) {
                    int sj = j0 + b2 - 1;
                    if (sj < 0 || sj >= Nn) continue;
                    conv += xs[si*128 + sj] * ka[a*3 + b2];
                }
            }
            if (itj < 20) {
                xv[k] += tau * (fv[k] - conv);
            } else {
                g_x[b*RSZ + e] = xv[k];
                g_r[b*RSZ + e] = fv[k] - conv;
            }
        }
    }
}

// ---------------- odd-symmetric expand value ----------------
__device__ inline float expand_val(const float* __restrict__ r, int b, int m, int n)
{
    if (m == 0 || m == 128 || n == 0 || n == 128) return 0.f;
    float s = 1.f; int mr, nc;
    if (m < 128) { mr = m - 1; } else { mr = 255 - m; s = -s; }
    if (n < 128) { nc = n - 1; } else { nc = 255 - n; s = -s; }
    return s * r[b*RSZ + mr*Nn + nc];
}

// ---------------- 256-pt Stockham FFT over lines (2 lines / 256-thread block) ----------------
// SIGN=+1: inverse (e^{+i...}), SIGN=-1: forward. scale applied at store.
// sel==0: in=g_CA out=g_CB ; sel==1: in=g_CB out=g_CA (channel 0 only).
template<int SIGN, bool COLS, bool EXPAND>
__global__ __launch_bounds__(256) void fft_kernel(int sel, float scale, int it)
{
    if (it >= g_K) return;
    __shared__ float2 bufA[2][256];
    __shared__ float2 bufB[2][256];
    const float2* __restrict__ in = sel ? g_CB : g_CA;
    float2* __restrict__ out      = sel ? g_CA : g_CB;

    int lid  = threadIdx.x >> 7;
    int t    = threadIdx.x & 127;
    int line = (blockIdx.x << 1) + lid;
    int b    = line >> 8;
    int pos  = line & 255;
    int base = (b*4) << 16;

#pragma unroll
    for (int h = 0; h < 2; h++) {
        int e = t + (h << 7);
        float2 v;
        if (EXPAND)    v = make_float2(expand_val(g_r, b, pos, e), 0.f);
        else if (COLS) v = in[base + e*NP + pos];
        else           v = in[base + pos*NP + e];
        bufA[lid][e] = v;
    }
    __syncthreads();

    float2* X = bufA[lid];
    float2* Y = bufB[lid];
#pragma unroll
    for (int k = 0; k < 8; k++) {
        int s = 1 << k;
        int p = t >> k;
        int q = t & (s - 1);
        float2 a = X[q + s*p];
        float2 c = X[q + s*(p + (128 >> k))];
        float ang = (float)SIGN * 6.283185307179586f * (float)p / (float)(256 >> k);
        float sn, cs;
        sincosf(ang, &sn, &cs);
        float2 sum = make_float2(a.x + c.x, a.y + c.y);
        float2 d   = make_float2(a.x - c.x, a.y - c.y);
        float2 dw  = make_float2(d.x*cs - d.y*sn, d.x*sn + d.y*cs);
        Y[q + s*(2*p)]     = sum;
        Y[q + s*(2*p + 1)] = dw;
        __syncthreads();
        float2* tmp = X; X = Y; Y = tmp;
    }

#pragma unroll
    for (int h = 0; h < 2; h++) {
        int e = t + (h << 7);
        float2 v = X[e];
        v.x *= scale; v.y *= scale;
        if (COLS) out[base + e*NP + pos] = v;
        else      out[base + pos*NP + e] = v;
    }
}

// ---------------- complex grouped 3x3 conv ----------------
// WID: 0=W1 1=W2 2=W3 3=W3T 4=W2T 5=W1T
// SHIFT_LOAD: read input through fftshift mapping (padding in shifted coords)
// SHIFT_STORE: write output through ifftshift mapping
template<int CIN, int COUT, int WID, bool SHIFT_LOAD, bool SHIFT_STORE, bool THETA>
__global__ __launch_bounds__(256) void convc_kernel(int sel,
                                                    const float* __restrict__ thr,
                                                    const float* __restrict__ thi, int it)
{
    if (it >= g_K) return;
    const float2* __restrict__ in = sel ? g_CB : g_CA;
    float2* __restrict__ out      = sel ? g_CA : g_CB;
    const float2* W =
        (WID == 0) ? g_W1 : (WID == 1) ? g_W2 : (WID == 2) ? g_W3 :
        (WID == 3) ? g_W3T : (WID == 4) ? g_W2T : g_W1T;

    int i  = blockIdx.x;
    int co = blockIdx.y;
    int b  = blockIdx.z;
    int j  = threadIdx.x;

    float2 w[CIN][9];
    const float2* Wp = W + ((b*COUT + co)*CIN)*9;
#pragma unroll
    for (int ci = 0; ci < CIN; ci++)
#pragma unroll
        for (int k = 0; k < 9; k++) w[ci][k] = Wp[ci*9 + k];

    float2 acc = make_float2(0.f, 0.f);
#pragma unroll
    for (int a = 0; a < 3; a++) {
        int si = i + a - 1;
        if (si < 0 || si >= NP) continue;
        int rbase = SHIFT_LOAD ? (((si + 128) & 255) * NP) : (si * NP);
#pragma unroll
        for (int b2 = 0; b2 < 3; b2++) {
            int sj = j + b2 - 1;
            if (sj < 0 || sj >= NP) continue;
            int cidx = SHIFT_LOAD ? ((sj + 128) & 255) : sj;
#pragma unroll
            for (int ci = 0; ci < CIN; ci++) {
                float2 v  = in[((b*4 + ci) << 16) + rbase + cidx];
                float2 ww = w[ci][a*3 + b2];
                acc.x += v.x*ww.x - v.y*ww.y;
                acc.y += v.x*ww.y + v.y*ww.x;
            }
        }
    }
    if (THETA) {
        float tr = thr[b*NSQ + i*NP + j];
        float ti = thi[b*NSQ + i*NP + j];
        acc = make_float2(acc.x*tr - acc.y*ti, acc.x*ti + acc.y*tr);
    }
    int oi = SHIFT_STORE ? ((i + 128) & 255) : i;
    int oj = SHIFT_STORE ? ((j + 128) & 255) : j;
    out[((b*4 + co) << 16) + oi*NP + oj] = acc;
}

// ---------------- x += Re(e) crop ----------------
__global__ void xupd_kernel(int it)
{
    if (it >= g_K) return;
    int tid = blockIdx.x*blockDim.x + threadIdx.x;
    if (tid >= Bn*RSZ) return;
    int b = tid / RSZ, rem = tid - b*RSZ;
    int i = rem / Nn, j = rem - i*Nn;
    g_x[tid] += g_CB[((b*4) << 16) + i*NP + j].x;
}

// ---------------- r = f - A x ----------------
__global__ void resid_kernel(const float* __restrict__ f, const float* __restrict__ kA, int it)
{
    if (it >= g_K) return;
    int tid = blockIdx.x*blockDim.x + threadIdx.x;
    if (tid >= Bn*RSZ) return;
    int b = tid / RSZ, rem = tid - b*RSZ;
    int i = rem / Nn, j = rem - i*Nn;
    float acc = 0.f;
#pragma unroll
    for (int a = 0; a < 3; a++) {
        int si = i + a - 1;
        if (si < 0 || si >= Nn) continue;
#pragma unroll
        for (int b2 = 0; b2 < 3; b2++) {
            int sj = j + b2 - 1;
            if (sj < 0 || sj >= Nn) continue;
            acc += g_x[b*RSZ + si*Nn + sj] * kA[b*9 + a*3 + b2];
        }
    }
    g_r[tid] = f[tid] - acc;
}

// ---------------- final norm ratio ----------------
__global__ __launch_bounds__(1024) void norm_kernel(const float* __restrict__ f, float* __restrict__ out)
{
    __shared__ float sr[1024], sf[1024];
    int t = threadIdx.x;
    float ar = 0.f, af = 0.f;
    for (int i = t; i < Bn*RSZ; i += 1024) {
        float rv = g_r[i]; ar += rv*rv;
        float fv = f[i];   af += fv*fv;
    }
    sr[t] = ar; sf[t] = af;
    __syncthreads();
    for (int s = 512; s > 0; s >>= 1) {
        if (t < s) { sr[t] += sr[t+s]; sf[t] += sf[t+s]; }
        __syncthreads();
    }
    if (t == 0) out[0] = sqrtf(sr[0] / sf[0]);
}

// ---------------- driver ----------------
extern "C" void kernel_launch(void* const* d_in, const int* in_sizes, int n_in,
                              void* d_out, int out_size, void* d_ws, size_t ws_size,
                              hipStream_t stream)
{
    const float* f   = (const float*)d_in[0];
    const float* kA  = (const float*)d_in[1];
    const float* w1r = (const float*)d_in[2];
    const float* w1i = (const float*)d_in[3];
    const float* w2r = (const float*)d_in[4];
    const float* w2i = (const float*)d_in[5];
    const float* w3r = (const float*)d_in[6];
    const float* w3i = (const float*)d_in[7];
    const float* thr = (const float*)d_in[8];
    const float* thi = (const float*)d_in[9];
    const int* epoch = (const int*)d_in[10];
    float* out = (float*)d_out;

    init_kernel<<<1, 256, 0, stream>>>(w1r, w1i, w2r, w2i, w3r, w3i, epoch);

    const int nP = (Bn*RSZ + 255) / 256;
    const float inv256 = 1.f / 256.f;

    for (int it = 0; it < 10; it++) {
        jacobi_kernel<<<16, 1024, 0, stream>>>(f, kA, it);
        // ifft2(expand(r)): rows (expand-fused) then cols, each scaled 1/256
        fft_kernel<1, false, true ><<<2048, 256, 0, stream>>>(1, inv256, it);  // -> CA
        fft_kernel<1, true,  false><<<2048, 256, 0, stream>>>(0, inv256, it);  // CA -> CB
        // conv stack (fftshift fused into conv1 load)
        convc_kernel<1,4,0,true, false,false><<<dim3(256,4,16), 256, 0, stream>>>(1, nullptr, nullptr, it); // CB->CA
        convc_kernel<4,4,1,false,false,false><<<dim3(256,4,16), 256, 0, stream>>>(0, nullptr, nullptr, it); // CA->CB
        convc_kernel<4,1,2,false,false,true ><<<dim3(256,1,16), 256, 0, stream>>>(1, thr, thi, it);         // CB->CA (*theta)
        // adjoint stack (ifftshift fused into last store)
        convc_kernel<1,4,3,false,false,false><<<dim3(256,4,16), 256, 0, stream>>>(0, nullptr, nullptr, it); // CA->CB
        convc_kernel<4,4,4,false,false,false><<<dim3(256,4,16), 256, 0, stream>>>(1, nullptr, nullptr, it); // CB->CA
        convc_kernel<4,1,5,false,true, false><<<dim3(256,1,16), 256, 0, stream>>>(0, nullptr, nullptr, it); // CA->CB
        // fft2: rows then cols, no scaling
        fft_kernel<-1, false, false><<<2048, 256, 0, stream>>>(1, 1.f, it);    // CB -> CA
        fft_kernel<-1, true,  false><<<2048, 256, 0, stream>>>(0, 1.f, it);    // CA -> CB
        xupd_kernel<<<nP, 256, 0, stream>>>(it);
        resid_kernel<<<nP, 256, 0, stream>>>(f, kA, it);
    }
    norm_kernel<<<1, 1024, 0, stream>>>(f, out);
}

// Round 2
// 1129.445 us; speedup vs baseline: 1.5182x; 1.5182x over previous
//
#include <hip/hip_runtime.h>
#include <math.h>

#define Bn  16
#define Nn  127
#define NP  256
#define NSQ (NP*NP)       // 65536
#define RSZ (Nn*Nn)       // 16129

// ---------------- static device workspace ----------------
__device__ float2 g_CA[Bn*4*NSQ];   // 33.5 MB
__device__ float2 g_CB[Bn*4*NSQ];   // 33.5 MB
__device__ float  g_x [Bn*RSZ];     // x after jacobi (written by jacobi)
__device__ float  g_xB[Bn*RSZ];     // x after spectral update (written by fused)
__device__ float  g_r [Bn*RSZ];
__device__ float2 g_W1 [Bn*4*9];
__device__ float2 g_W1T[Bn*4*9];
__device__ float2 g_W2 [Bn*16*9];
__device__ float2 g_W2T[Bn*16*9];
__device__ float2 g_W3 [Bn*4*9];
__device__ float2 g_W3T[Bn*4*9];
__device__ float2 g_twid[128];      // e^{+2pi i m/256}
__device__ int    g_K;

// ---------------- init: K, zero xB, twiddles, canonical weights ----------------
__global__ void init_kernel(const float* __restrict__ w1r, const float* __restrict__ w1i,
                            const float* __restrict__ w2r, const float* __restrict__ w2i,
                            const float* __restrict__ w3r, const float* __restrict__ w3i,
                            const int* __restrict__ epoch)
{
    int tid = threadIdx.x;
    if (tid == 0) {
        int e = epoch[0];
        int K = (e - 1) / 40 + 1;
        if (K > 10) K = 10;
        if (K < 1)  K = 1;
        g_K = K;
    }
    for (int i = tid; i < Bn*RSZ; i += 256) g_xB[i] = 0.f;
    if (tid < 128) {
        float sn, cs;
        sincosf(6.283185307179586f * (float)tid / 256.f, &sn, &cs);
        g_twid[tid] = make_float2(cs, sn);
    }

    for (int o = tid; o < Bn*36; o += 256) {
        int k = o % 9;
        int a = k / 3, bb = k % 3;
        int c = (o / 9) % 4;
        int b = o / 36;
        int src = b*36 + c*9 + bb*3 + a;
        g_W1 [o] = make_float2(w1r[o],  w1i[o]);
        g_W1T[o] = make_float2(w1r[src], -w1i[src]);
        g_W3 [o] = make_float2(w3r[o],  w3i[o]);
        g_W3T[o] = make_float2(w3r[src], -w3i[src]);
    }
    for (int o = tid; o < Bn*144; o += 256) {
        int k = o % 9;
        int a = k / 3, bb = k % 3;
        int ci = (o / 9) % 4;
        int co = (o / 36) % 4;
        int b  = o / 144;
        int src = b*144 + ci*36 + co*9 + bb*3 + a;
        g_W2 [o] = make_float2(w2r[o],  w2i[o]);
        g_W2T[o] = make_float2(w2r[src], -w2i[src]);
    }
}

// ---------------- Jacobi: halo-tiled, 20 steps + residual, 256 blocks ----------------
// Tile 32x32, halo 21 -> region 74x74. Buffer 76 rows x 80 cols (guard ring, pad).
// Region point (rr,cc) at buffer [1+rr][3+cc]. Correctness: after step s the
// buffer equals true x_s on tile dilated by (21-s); after 20 steps valid on
// tile+1, enough for the residual conv on the tile.
__global__ __launch_bounds__(512) void jacobi_kernel(const float* __restrict__ f,
                                                     const float* __restrict__ kA, int it)
{
    if (it >= g_K) return;
    __shared__ float buf0[76*80];
    __shared__ float buf1[76*80];
    const int tid = threadIdx.x;
    const int b  = blockIdx.z;
    const int ti = blockIdx.y, tj = blockIdx.x;
    const int gr0 = ti*32 - 21, gc0 = tj*32 - 21;

    float ka[9];
#pragma unroll
    for (int k = 0; k < 9; ++k) ka[k] = kA[b*9 + k];
    const float tau = 0.5f / ka[4];

    for (int i = tid; i < 76*80; i += 512) { buf0[i] = 0.f; buf1[i] = 0.f; }

    int   off[6]; float fv0[6], fv1[6], mm0[6], mm1[6], x00[6], x01[6];
#pragma unroll
    for (int q = 0; q < 6; ++q) {
        int idx = tid + q*512;
        bool valid = idx < 74*37;
        int rr = idx / 37, pp = idx - rr*37;
        int gr = gr0 + rr;
        int gc = gc0 + pp*2;
        bool rowok = valid && gr >= 0 && gr < Nn;
        bool c0 = rowok && gc >= 0 && gc < Nn;
        bool c1 = rowok && (gc+1) >= 0 && (gc+1) < Nn;
        off[q] = valid ? ((1+rr)*80 + 3 + 2*pp) : -1;
        mm0[q] = c0 ? 1.f : 0.f;
        mm1[q] = c1 ? 1.f : 0.f;
        fv0[q] = c0 ? f[b*RSZ + gr*Nn + gc]     : 0.f;
        fv1[q] = c1 ? f[b*RSZ + gr*Nn + gc + 1] : 0.f;
        x00[q] = c0 ? g_xB[b*RSZ + gr*Nn + gc]     : 0.f;
        x01[q] = c1 ? g_xB[b*RSZ + gr*Nn + gc + 1] : 0.f;
    }
    __syncthreads();
#pragma unroll
    for (int q = 0; q < 6; ++q) {
        if (off[q] < 0) continue;
        buf0[off[q]]     = x00[q];
        buf0[off[q] + 1] = x01[q];
    }

    for (int s = 0; s < 20; ++s) {
        __syncthreads();
        const float* ob = (s & 1) ? buf1 : buf0;
        float*       nb = (s & 1) ? buf0 : buf1;
#pragma unroll
        for (int q = 0; q < 6; ++q) {
            int o = off[q];
            if (o < 0) continue;
            float2 a0 = *(const float2*)(ob + o - 81);
            float2 b0 = *(const float2*)(ob + o - 79);
            float2 a1 = *(const float2*)(ob + o - 1);
            float2 b1 = *(const float2*)(ob + o + 1);
            float2 a2 = *(const float2*)(ob + o + 79);
            float2 b2 = *(const float2*)(ob + o + 81);
            float c0 = ka[0]*a0.x + ka[1]*a0.y + ka[2]*b0.x
                     + ka[3]*a1.x + ka[4]*a1.y + ka[5]*b1.x
                     + ka[6]*a2.x + ka[7]*a2.y + ka[8]*b2.x;
            float c1 = ka[0]*a0.y + ka[1]*b0.x + ka[2]*b0.y
                     + ka[3]*a1.y + ka[4]*b1.x + ka[5]*b1.y
                     + ka[6]*a2.y + ka[7]*b2.x + ka[8]*b2.y;
            nb[o]     = (a1.y + tau*(fv0[q] - c0)) * mm0[q];
            nb[o + 1] = (b1.x + tau*(fv1[q] - c1)) * mm1[q];
        }
    }
    __syncthreads();
    // final x in buf0; write x and r = f - A x on the tile
    for (int idx = tid; idx < 32*32; idx += 512) {
        int a = idx >> 5, c = idx & 31;
        int gr = ti*32 + a, gc = tj*32 + c;
        if (gr >= Nn || gc >= Nn) continue;
        int o = (22 + a)*80 + 24 + c;
        float conv = ka[0]*buf0[o-81] + ka[1]*buf0[o-80] + ka[2]*buf0[o-79]
                   + ka[3]*buf0[o-1]  + ka[4]*buf0[o]    + ka[5]*buf0[o+1]
                   + ka[6]*buf0[o+79] + ka[7]*buf0[o+80] + ka[8]*buf0[o+81];
        int g = b*RSZ + gr*Nn + gc;
        g_x[g] = buf0[o];
        g_r[g] = f[g] - conv;
    }
}

// ---------------- odd-symmetric expand value ----------------
__device__ inline float expand_val(const float* __restrict__ r, int b, int m, int n)
{
    if (m == 0 || m == 128 || n == 0 || n == 128) return 0.f;
    float s = 1.f; int mr, nc;
    if (m < 128) { mr = m - 1; } else { mr = 255 - m; s = -s; }
    if (n < 128) { nc = n - 1; } else { nc = 255 - n; s = -s; }
    return s * r[b*RSZ + mr*Nn + nc];
}

// ---------------- 256-pt Stockham FFT, 8 lines per block ----------------
template<int SIGN, bool COLS, bool EXPAND>
__global__ __launch_bounds__(256) void fft_kernel(int sel, float scale, int it)
{
    if (it >= g_K) return;
    __shared__ float2 bufA[2][256];
    __shared__ float2 bufB[2][256];
    __shared__ float2 tw[128];
    const float2* __restrict__ in = sel ? g_CB : g_CA;
    float2* __restrict__ out      = sel ? g_CA : g_CB;

    for (int m = threadIdx.x; m < 128; m += 256) tw[m] = g_twid[m];

    int lid = threadIdx.x >> 7;
    int t   = threadIdx.x & 127;

    for (int lp = 0; lp < 4; ++lp) {
        __syncthreads();
        int line = blockIdx.x*8 + lp*2 + lid;
        int b    = line >> 8;
        int pos  = line & 255;
        int base = (b*4) << 16;

#pragma unroll
        for (int h = 0; h < 2; ++h) {
            int e = t + (h << 7);
            float2 v;
            if (EXPAND)    v = make_float2(expand_val(g_r, b, pos, e), 0.f);
            else if (COLS) v = in[base + e*NP + pos];
            else           v = in[base + pos*NP + e];
            bufA[lid][e] = v;
        }
        __syncthreads();

        float2* X = bufA[lid];
        float2* Y = bufB[lid];
#pragma unroll
        for (int k = 0; k < 8; ++k) {
            int s = 1 << k;
            int p = t >> k;
            int q = t & (s - 1);
            float2 a = X[q + s*p];
            float2 c = X[q + s*(p + (128 >> k))];
            float2 w = tw[p << k];
            float cs = w.x;
            float sn = (SIGN > 0) ? w.y : -w.y;
            float2 sum = make_float2(a.x + c.x, a.y + c.y);
            float2 d   = make_float2(a.x - c.x, a.y - c.y);
            float2 dw  = make_float2(d.x*cs - d.y*sn, d.x*sn + d.y*cs);
            Y[q + s*(2*p)]     = sum;
            Y[q + s*(2*p + 1)] = dw;
            __syncthreads();
            float2* tmp = X; X = Y; Y = tmp;
        }

#pragma unroll
        for (int h = 0; h < 2; ++h) {
            int e = t + (h << 7);
            float2 v = X[e];
            v.x *= scale; v.y *= scale;
            if (COLS) out[base + e*NP + pos] = v;
            else      out[base + pos*NP + e] = v;
        }
    }
}

// ---------------- complex grouped 3x3 conv, 16 rows/thread, sliding window ----------------
template<int CIN, int COUT, int WID, bool SHIFT_LOAD, bool SHIFT_STORE, bool THETA>
__global__ __launch_bounds__(256) void convc_kernel(int sel,
                                                    const float* __restrict__ thr,
                                                    const float* __restrict__ thi, int it)
{
    if (it >= g_K) return;
    const float2* __restrict__ in = sel ? g_CB : g_CA;
    float2* __restrict__ out      = sel ? g_CA : g_CB;
    const float2* W =
        (WID == 0) ? g_W1 : (WID == 1) ? g_W2 : (WID == 2) ? g_W3 :
        (WID == 3) ? g_W3T : (WID == 4) ? g_W2T : g_W1T;

    const int rg = blockIdx.x;
    const int co = blockIdx.y;
    const int b  = blockIdx.z;
    const int j  = threadIdx.x;

    float2 w[CIN][9];
    const float2* Wp = W + ((b*COUT + co)*CIN)*9;
#pragma unroll
    for (int ci = 0; ci < CIN; ++ci)
#pragma unroll
        for (int k = 0; k < 9; ++k) w[ci][k] = Wp[ci*9 + k];

    auto ld = [&](int ci, int si, int sj) -> float2 {
        if (si < 0 || si >= NP || sj < 0 || sj >= NP) return make_float2(0.f, 0.f);
        int r = SHIFT_LOAD ? ((si + 128) & 255) : si;
        int c = SHIFT_LOAD ? ((sj + 128) & 255) : sj;
        return in[((b*4 + ci) << 16) + r*NP + c];
    };

    float2 win[CIN][3][3];
    const int i0 = rg * 16;
#pragma unroll
    for (int ci = 0; ci < CIN; ++ci)
#pragma unroll
        for (int c = 0; c < 3; ++c) {
            win[ci][0][c] = ld(ci, i0 - 1, j - 1 + c);
            win[ci][1][c] = ld(ci, i0,     j - 1 + c);
        }

    for (int i = i0; i < i0 + 16; ++i) {
#pragma unroll
        for (int ci = 0; ci < CIN; ++ci)
#pragma unroll
            for (int c = 0; c < 3; ++c)
                win[ci][2][c] = ld(ci, i + 1, j - 1 + c);

        float2 acc = make_float2(0.f, 0.f);
#pragma unroll
        for (int ci = 0; ci < CIN; ++ci)
#pragma unroll
            for (int r = 0; r < 3; ++r)
#pragma unroll
                for (int c = 0; c < 3; ++c) {
                    float2 v  = win[ci][r][c];
                    float2 ww = w[ci][r*3 + c];
                    acc.x += v.x*ww.x - v.y*ww.y;
                    acc.y += v.x*ww.y + v.y*ww.x;
                }
        if (THETA) {
            float tr = thr[b*NSQ + i*NP + j];
            float ti2 = thi[b*NSQ + i*NP + j];
            acc = make_float2(acc.x*tr - acc.y*ti2, acc.x*ti2 + acc.y*tr);
        }
        int oi = SHIFT_STORE ? ((i + 128) & 255) : i;
        int oj = SHIFT_STORE ? ((j + 128) & 255) : j;
        out[((b*4 + co) << 16) + oi*NP + oj] = acc;

#pragma unroll
        for (int ci = 0; ci < CIN; ++ci)
#pragma unroll
            for (int c = 0; c < 3; ++c) {
                win[ci][0][c] = win[ci][1][c];
                win[ci][1][c] = win[ci][2][c];
            }
    }
}

// ---------------- fused: x_new = x + e ; r = f - A x - A e ----------------
__global__ void xupd_resid_kernel(const float* __restrict__ f, const float* __restrict__ kA, int it)
{
    if (it >= g_K) return;
    int tid = blockIdx.x*blockDim.x + threadIdx.x;
    if (tid >= Bn*RSZ) return;
    int b = tid / RSZ, rem = tid - b*RSZ;
    int i = rem / Nn, j = rem - i*Nn;
    const float2* e = g_CB + ((b*4) << 16);
    float acc = 0.f;
#pragma unroll
    for (int a = 0; a < 3; ++a) {
        int si = i + a - 1;
        if (si < 0 || si >= Nn) continue;
#pragma unroll
        for (int b2 = 0; b2 < 3; ++b2) {
            int sj = j + b2 - 1;
            if (sj < 0 || sj >= Nn) continue;
            float xv = g_x[b*RSZ + si*Nn + sj] + e[si*NP + sj].x;
            acc += xv * kA[b*9 + a*3 + b2];
        }
    }
    g_xB[tid] = g_x[tid] + e[i*NP + j].x;
    g_r[tid]  = f[tid] - acc;
}

// ---------------- final norm ratio ----------------
__global__ __launch_bounds__(1024) void norm_kernel(const float* __restrict__ f, float* __restrict__ out)
{
    __shared__ float sr[1024], sf[1024];
    int t = threadIdx.x;
    float ar = 0.f, af = 0.f;
    for (int i = t; i < Bn*RSZ; i += 1024) {
        float rv = g_r[i]; ar += rv*rv;
        float fv = f[i];   af += fv*fv;
    }
    sr[t] = ar; sf[t] = af;
    __syncthreads();
    for (int s = 512; s > 0; s >>= 1) {
        if (t < s) { sr[t] += sr[t+s]; sf[t] += sf[t+s]; }
        __syncthreads();
    }
    if (t == 0) out[0] = sqrtf(sr[0] / sf[0]);
}

// ---------------- driver ----------------
extern "C" void kernel_launch(void* const* d_in, const int* in_sizes, int n_in,
                              void* d_out, int out_size, void* d_ws, size_t ws_size,
                              hipStream_t stream)
{
    const float* f   = (const float*)d_in[0];
    const float* kA  = (const float*)d_in[1];
    const float* w1r = (const float*)d_in[2];
    const float* w1i = (const float*)d_in[3];
    const float* w2r = (const float*)d_in[4];
    const float* w2i = (const float*)d_in[5];
    const float* w3r = (const float*)d_in[6];
    const float* w3i = (const float*)d_in[7];
    const float* thr = (const float*)d_in[8];
    const float* thi = (const float*)d_in[9];
    const int* epoch = (const int*)d_in[10];
    float* out = (float*)d_out;

    init_kernel<<<1, 256, 0, stream>>>(w1r, w1i, w2r, w2i, w3r, w3i, epoch);

    const int nP = (Bn*RSZ + 255) / 256;
    const float inv256 = 1.f / 256.f;

    for (int it = 0; it < 10; it++) {
        jacobi_kernel<<<dim3(4,4,16), 512, 0, stream>>>(f, kA, it);
        fft_kernel<1, false, true ><<<512, 256, 0, stream>>>(1, inv256, it);  // expand rows -> CA
        fft_kernel<1, true,  false><<<512, 256, 0, stream>>>(0, inv256, it);  // CA -> CB
        convc_kernel<1,4,0,true, false,false><<<dim3(16,4,16), 256, 0, stream>>>(1, nullptr, nullptr, it); // CB->CA
        convc_kernel<4,4,1,false,false,false><<<dim3(16,4,16), 256, 0, stream>>>(0, nullptr, nullptr, it); // CA->CB
        convc_kernel<4,1,2,false,false,true ><<<dim3(16,1,16), 256, 0, stream>>>(1, thr, thi, it);         // CB->CA
        convc_kernel<1,4,3,false,false,false><<<dim3(16,4,16), 256, 0, stream>>>(0, nullptr, nullptr, it); // CA->CB
        convc_kernel<4,4,4,false,false,false><<<dim3(16,4,16), 256, 0, stream>>>(1, nullptr, nullptr, it); // CB->CA
        convc_kernel<4,1,5,false,true, false><<<dim3(16,1,16), 256, 0, stream>>>(0, nullptr, nullptr, it); // CA->CB
        fft_kernel<-1, false, false><<<512, 256, 0, stream>>>(1, 1.f, it);    // CB -> CA
        fft_kernel<-1, true,  false><<<512, 256, 0, stream>>>(0, 1.f, it);    // CA -> CB
        xupd_resid_kernel<<<nP, 256, 0, stream>>>(f, kA, it);
    }
    norm_kernel<<<1, 1024, 0, stream>>>(f, out);
}